// Round 10
// baseline (2434.494 us; speedup 1.0000x reference)
//
#include <hip/hip_runtime.h>

#define N_NODES 50000
#define N_EDGES 800000
#define N_GRAPHS 256
#define N_LAYERS 3
#define DIM 300
#define HSTR 320
#define NFEAT 128
#define EFEAT 16
#define OUTD 128
#define BN_EPS 1e-5f

typedef __attribute__((ext_vector_type(8))) short bfrag8;   // 8 bf16 = 4 VGPR (MFMA A/B operand)
typedef __attribute__((ext_vector_type(4))) float facc4;    // MFMA C/D
typedef __attribute__((ext_vector_type(4))) unsigned short us4;
typedef __attribute__((ext_vector_type(8))) unsigned short us8;
typedef __attribute__((ext_vector_type(2))) float f32x2;    // -> v_pk_fma_f32

// ---------------- bf16 helpers (RNE) + hi/lo split ----------------
__device__ __forceinline__ unsigned short f2bf(float f) {
    unsigned u = __float_as_uint(f);
    unsigned r = ((u >> 16) & 1u) + 0x7fffu;
    return (unsigned short)((u + r) >> 16);
}
__device__ __forceinline__ float bf2f(unsigned short h) {
    return __uint_as_float(((unsigned)h) << 16);
}
__device__ __forceinline__ void split2(float v, unsigned short& h, unsigned short& l) {
    h = f2bf(v);
    l = f2bf(v - bf2f(h));
}

// async global->LDS, 16B per lane. LDS dest = uniform base + lane*16 (HW rule).
__device__ __forceinline__ void load_lds16(const void* gsrc, void* ldsdst) {
    __builtin_amdgcn_global_load_lds(
        (const __attribute__((address_space(1))) unsigned int*)gsrc,
        (__attribute__((address_space(3))) unsigned int*)ldsdst,
        16, 0, 0);
}

#define MFMA16(a, b, c) __builtin_amdgcn_mfma_f32_16x16x32_bf16(a, b, c, 0, 0, 0)

// ---------------------------------------------------------------------------
// fp32 -> bf16 (hi only), vectorized
// ---------------------------------------------------------------------------
__global__ __launch_bounds__(256) void tobf4(
    const float* __restrict__ x, unsigned short* __restrict__ H, int n4)
{
    int i = blockIdx.x * 256 + threadIdx.x;
    if (i >= n4) return;
    float4 v = ((const float4*)x)[i];
    us4 h;
    h.x = f2bf(v.x); h.y = f2bf(v.y); h.z = f2bf(v.z); h.w = f2bf(v.w);
    ((us4*)H)[i] = h;
}

// ---------------------------------------------------------------------------
// weight conversion: W fp32 [K][N] -> transposed padded hi/lo planes [Np][Kp]
// ---------------------------------------------------------------------------
__global__ __launch_bounds__(256) void conv_wt(
    const float* __restrict__ W, unsigned short* __restrict__ H,
    unsigned short* __restrict__ L, int K, int N, int Kp, int Np)
{
    int idx = blockIdx.x * 256 + threadIdx.x;
    if (idx >= Np * Kp) return;
    int n = idx / Kp;
    int k = idx - n * Kp;
    float v = (n < N && k < K) ? W[(size_t)k * N + n] : 0.f;
    unsigned short h, l;
    split2(v, h, l);
    H[idx] = h;
    L[idx] = l;
}

// ---------------------------------------------------------------------------
// bf16 MFMA GEMM: A plain bf16 [M][Kp]; B transposed hi/lo planes [Np][Kp].
// acc = Ah*Bh + Ah*Bl (2 MFMA/tile). Block 128x128, BK=32, 4 waves 2x2.
// Output: fp32 C (ldc) if non-null, else bf16 Cb (ldcb). Optional stat epi.
// ---------------------------------------------------------------------------
__global__ __launch_bounds__(256, 2) void gemm_pp(
    const unsigned short* __restrict__ Ah,
    const unsigned short* __restrict__ Bth, const unsigned short* __restrict__ Btl,
    const float* __restrict__ bias, float* __restrict__ C, int ldc,
    unsigned short* __restrict__ Cb, int ldcb,
    int M, int N, int Kp, float* __restrict__ stats)
{
    __shared__ unsigned short lds[12288];   // 24 KB
    const int tid = threadIdx.x;
    const int lane = tid & 63;
    const int w = tid >> 6;
    const int m0 = blockIdx.x * 128;
    const int n0 = blockIdx.y * 128;
    const int wm = (w & 1) * 64;
    const int wn = (w >> 1) * 64;

    const int srow = lane >> 2;
    const int scol = (lane & 3) * 8;

    const unsigned short* gp[6];
    unsigned loff[6];
#pragma unroll
    for (int i = 0; i < 6; ++i) {
        int c = w * 6 + i;
        const unsigned short* pl = (c < 8) ? Ah : (c < 16) ? Bth : Btl;
        int rowg;
        if (c < 8) {
            rowg = m0 + (c & 7) * 16 + srow;
            rowg = min(rowg, M - 1);
        } else {
            rowg = n0 + (c & 7) * 16 + srow;
        }
        gp[i] = pl + (size_t)rowg * Kp + scol;
        loff[i] = c * 512;
    }

    facc4 acc[4][4];
    facc4 zero = {0.f, 0.f, 0.f, 0.f};
#pragma unroll
    for (int i = 0; i < 4; ++i)
#pragma unroll
        for (int j = 0; j < 4; ++j) acc[i][j] = zero;

    const int fr = lane & 15;
    const int fq = (lane >> 4) * 8;

    for (int k0 = 0; k0 < Kp; k0 += 32) {
#pragma unroll
        for (int i = 0; i < 6; ++i) {
            load_lds16(gp[i], &lds[loff[i]]);
            gp[i] += 32;
        }
        __syncthreads();

        bfrag8 ah[4], bh[4], bl[4];
#pragma unroll
        for (int t = 0; t < 4; ++t) {
            int ar = wm + t * 16 + fr;
            ah[t] = *(const bfrag8*)&lds[ar * 32 + fq];
            int br = wn + t * 16 + fr;
            bh[t] = *(const bfrag8*)&lds[4096 + br * 32 + fq];
            bl[t] = *(const bfrag8*)&lds[8192 + br * 32 + fq];
        }
#pragma unroll
        for (int i = 0; i < 4; ++i)
#pragma unroll
            for (int j = 0; j < 4; ++j) {
                acc[i][j] = MFMA16(ah[i], bh[j], acc[i][j]);
                acc[i][j] = MFMA16(ah[i], bl[j], acc[i][j]);
            }
        __syncthreads();
    }

    // epilogue: C/D layout col=lane&15, row=(lane>>4)*4+reg
#pragma unroll
    for (int i = 0; i < 4; ++i)
#pragma unroll
        for (int j = 0; j < 4; ++j) {
            int col = n0 + wn + j * 16 + (lane & 15);
            if (col >= N) continue;
            float bv = bias[col];
#pragma unroll
            for (int r = 0; r < 4; ++r) {
                int row = m0 + wm + i * 16 + (lane >> 4) * 4 + r;
                if (row < M) {
                    float y = acc[i][j][r] + bv;
                    if (C != nullptr) C[(size_t)row * ldc + col] = y;
                    else Cb[(size_t)row * ldcb + col] = f2bf(y);
                }
            }
        }

    if (stats != nullptr) {
#pragma unroll
        for (int j = 0; j < 4; ++j) {
            int col = n0 + wn + j * 16 + (lane & 15);
            float cs = 0.f, cq = 0.f;
            if (col < N) {
                float bv = bias[col];
#pragma unroll
                for (int i = 0; i < 4; ++i)
#pragma unroll
                    for (int r = 0; r < 4; ++r) {
                        int row = m0 + wm + i * 16 + (lane >> 4) * 4 + r;
                        if (row < M) {
                            float y = acc[i][j][r] + bv;
                            cs += y;
                            cq = fmaf(y, y, cq);
                        }
                    }
            }
            cs += __shfl_xor(cs, 16, 64); cq += __shfl_xor(cq, 16, 64);
            cs += __shfl_xor(cs, 32, 64); cq += __shfl_xor(cq, 32, 64);
            if ((lane >> 4) == 0 && col < N) {
                atomicAdd(&stats[col], cs);
                atomicAdd(&stats[N + col], cq);
            }
        }
    }
}

// ---------------------------------------------------------------------------
// bf16 MFMA GEMM, A bf16 (x1b, stride lda) with fused BN-affine+ReLU applied
// during staging (abn = [a K | b K], y = relu(bf2f(x)*a+b)) -> bf16.
// LDS 24KB: A | Bh | Bl. Output fp32 C (ldc). Column-stat epilogue for BN2.
// ---------------------------------------------------------------------------
__global__ __launch_bounds__(256, 2) void gemm_af(
    const unsigned short* __restrict__ A, int lda,
    const unsigned short* __restrict__ Bth, const unsigned short* __restrict__ Btl,
    const float* __restrict__ bias, float* __restrict__ C, int ldc,
    int M, int N, int K, int Kp,
    const float* __restrict__ abn, float* __restrict__ stats)
{
    __shared__ unsigned short lds[12288];
    const int tid = threadIdx.x;
    const int lane = tid & 63;
    const int w = tid >> 6;
    const int m0 = blockIdx.x * 128;
    const int n0 = blockIdx.y * 128;
    const int wm = (w & 1) * 64;
    const int wn = (w >> 1) * 64;

    const int srow = lane >> 2;
    const int scol = (lane & 3) * 8;

    const unsigned short* gpb[4];
    unsigned loffb[4];
#pragma unroll
    for (int i = 0; i < 4; ++i) {
        int c = w * 4 + i;
        const unsigned short* pl = (c < 8) ? Bth : Btl;
        int rowg = n0 + (c & 7) * 16 + srow;
        gpb[i] = pl + (size_t)rowg * Kp + scol;
        loffb[i] = 4096 + c * 512;
    }

    facc4 acc[4][4];
    facc4 zero = {0.f, 0.f, 0.f, 0.f};
#pragma unroll
    for (int i = 0; i < 4; ++i)
#pragma unroll
        for (int j = 0; j < 4; ++j) acc[i][j] = zero;

    const int fr = lane & 15;
    const int fq = (lane >> 4) * 8;

    for (int k0 = 0; k0 < Kp; k0 += 32) {
#pragma unroll
        for (int i = 0; i < 4; ++i) {
            load_lds16(gpb[i], &lds[loffb[i]]);
            gpb[i] += 32;
        }
        // A bf16 -> BN affine + relu -> bf16 into LDS (128 rows x 32 k)
#pragma unroll
        for (int i = 0; i < 4; ++i) {
            int idx = tid + i * 256;
            int row = idx >> 3;
            int q4 = idx & 7;
            int rg = min(m0 + row, M - 1);
            int kk = k0 + q4 * 4;
            us4 h;
            if (kk < K) {
                us4 xb = *(const us4*)&A[(size_t)rg * lda + kk];
                float4 sa = *(const float4*)&abn[kk];
                float4 sb = *(const float4*)&abn[K + kk];
                h.x = f2bf(fmaxf(fmaf(bf2f(xb.x), sa.x, sb.x), 0.f));
                h.y = f2bf(fmaxf(fmaf(bf2f(xb.y), sa.y, sb.y), 0.f));
                h.z = f2bf(fmaxf(fmaf(bf2f(xb.z), sa.z, sb.z), 0.f));
                h.w = f2bf(fmaxf(fmaf(bf2f(xb.w), sa.w, sb.w), 0.f));
            } else {
                h.x = 0; h.y = 0; h.z = 0; h.w = 0;
            }
            *(us4*)&lds[row * 32 + q4 * 4] = h;
        }
        __syncthreads();

        bfrag8 ah[4], bh[4], bl[4];
#pragma unroll
        for (int t = 0; t < 4; ++t) {
            int ar = wm + t * 16 + fr;
            ah[t] = *(const bfrag8*)&lds[ar * 32 + fq];
            int br = wn + t * 16 + fr;
            bh[t] = *(const bfrag8*)&lds[4096 + br * 32 + fq];
            bl[t] = *(const bfrag8*)&lds[8192 + br * 32 + fq];
        }
#pragma unroll
        for (int i = 0; i < 4; ++i)
#pragma unroll
            for (int j = 0; j < 4; ++j) {
                acc[i][j] = MFMA16(ah[i], bh[j], acc[i][j]);
                acc[i][j] = MFMA16(ah[i], bl[j], acc[i][j]);
            }
        __syncthreads();
    }

#pragma unroll
    for (int i = 0; i < 4; ++i)
#pragma unroll
        for (int j = 0; j < 4; ++j) {
            int col = n0 + wn + j * 16 + (lane & 15);
            if (col >= N) continue;
            float bv = bias[col];
#pragma unroll
            for (int r = 0; r < 4; ++r) {
                int row = m0 + wm + i * 16 + (lane >> 4) * 4 + r;
                if (row < M)
                    C[(size_t)row * ldc + col] = acc[i][j][r] + bv;
            }
        }

    if (stats != nullptr) {
#pragma unroll
        for (int j = 0; j < 4; ++j) {
            int col = n0 + wn + j * 16 + (lane & 15);
            float cs = 0.f, cq = 0.f;
            if (col < N) {
                float bv = bias[col];
#pragma unroll
                for (int i = 0; i < 4; ++i)
#pragma unroll
                    for (int r = 0; r < 4; ++r) {
                        int row = m0 + wm + i * 16 + (lane >> 4) * 4 + r;
                        if (row < M) {
                            float y = acc[i][j][r] + bv;
                            cs += y;
                            cq = fmaf(y, y, cq);
                        }
                    }
            }
            cs += __shfl_xor(cs, 16, 64); cq += __shfl_xor(cq, 16, 64);
            cs += __shfl_xor(cs, 32, 64); cq += __shfl_xor(cq, 32, 64);
            if ((lane >> 4) == 0 && col < N) {
                atomicAdd(&stats[col], cs);
                atomicAdd(&stats[N + col], cq);
            }
        }
    }
}

// ---------------------------------------------------------------------------
// CSR build (dst-sorted). P[v] = end offset after fill.
// ---------------------------------------------------------------------------
__global__ __launch_bounds__(256) void csr_count(const int* __restrict__ dst, int* __restrict__ P)
{
    int e = blockIdx.x * 256 + threadIdx.x;
    if (e < N_EDGES) atomicAdd(&P[dst[e] + 1], 1);
}

__global__ __launch_bounds__(1024) void csr_scan(int* __restrict__ P)
{
    __shared__ int part[1024];
    const int t = threadIdx.x;
    const int CH = 49;
    int i0 = t * CH;
    int s = 0;
    for (int i = i0; i < i0 + CH; ++i) {
        if (i <= N_NODES) { s += P[i]; P[i] = s; }
    }
    part[t] = s;
    __syncthreads();
    if (t == 0) {
        int run = 0;
        for (int k = 0; k < 1024; ++k) { int tmp = part[k]; part[k] = run; run += tmp; }
    }
    __syncthreads();
    int off = part[t];
    for (int i = i0; i < i0 + CH; ++i) {
        if (i <= N_NODES) P[i] += off;
    }
}

__global__ __launch_bounds__(256) void csr_fill(
    const int* __restrict__ dst, int* __restrict__ P, int* __restrict__ eids)
{
    int e = blockIdx.x * 256 + threadIdx.x;
    if (e < N_EDGES) {
        int pos = atomicAdd(&P[dst[e]], 1);
        eids[pos] = e;
    }
}

// ---------------------------------------------------------------------------
// Re-sort src + edge_feat(->bf16) into CSR edge order. Runs once.
// ---------------------------------------------------------------------------
__global__ __launch_bounds__(256) void edge_pack_bf(
    const int* __restrict__ src, const int* __restrict__ eids,
    const float* __restrict__ edge_feat, int* __restrict__ es,
    unsigned short* __restrict__ efsb)
{
    int j = blockIdx.x * 256 + threadIdx.x;
    if (j >= N_EDGES) return;
    int e = eids[j];
    es[j] = src[e];
    const float* sp = edge_feat + (size_t)e * EFEAT;
    us8 o0, o1;
#pragma unroll
    for (int k = 0; k < 8; ++k) {
        o0[k] = f2bf(sp[k]);
        o1[k] = f2bf(sp[8 + k]);
    }
    *(us8*)&efsb[(size_t)j * EFEAT] = o0;
    *(us8*)&efsb[(size_t)j * EFEAT + 8] = o1;
}

// ---------------------------------------------------------------------------
// Gather v8: ONE wave per node, fp32 hn rows STRIDE 320 zero-padded
// (unconditional loads, no cndmask), he computed with f32x2 packed FMA
// (v_pk_fma_f32: 5 chunks as 2 pairs + 1 scalar -> ~48 issue slots vs 80),
// edge loop unrolled x4 (20 outstanding row loads). Output bf16 [N][320].
// ---------------------------------------------------------------------------
__device__ __forceinline__ void he_edge(
    const unsigned short* __restrict__ efsb, long j,
    const f32x2 wr01[EFEAT], const f32x2 wr23[EFEAT], const float wr4[EFEAT],
    f32x2 eb01, f32x2 eb23, float eb4,
    f32x2& he01, f32x2& he23, float& he4)
{
    us8 p0 = *(const us8*)&efsb[j * EFEAT];
    us8 p1 = *(const us8*)&efsb[j * EFEAT + 8];
    he01 = eb01; he23 = eb23; he4 = eb4;
#pragma unroll
    for (int k = 0; k < EFEAT; ++k) {
        float e = bf2f(k < 8 ? p0[k] : p1[k - 8]);
        f32x2 e2 = {e, e};
        he01 = __builtin_elementwise_fma(e2, wr01[k], he01);
        he23 = __builtin_elementwise_fma(e2, wr23[k], he23);
        he4 = fmaf(e, wr4[k], he4);
    }
}

__global__ __launch_bounds__(256) void gather_agg8(
    const float* __restrict__ hn, const unsigned short* __restrict__ efsb,
    const int* __restrict__ es, const int* __restrict__ P,
    const float* __restrict__ eW, const float* __restrict__ eb,
    unsigned short* __restrict__ aggH)
{
    const int v = blockIdx.x * 4 + (threadIdx.x >> 6);
    if (v >= N_NODES) return;
    const int lane = threadIdx.x & 63;
    const int d4 = lane + 256;
    const bool dv4 = d4 < DIM;

    f32x2 wr01[EFEAT], wr23[EFEAT];
    float wr4[EFEAT];
#pragma unroll
    for (int k = 0; k < EFEAT; ++k) {
        wr01[k].x = eW[k * DIM + lane];
        wr01[k].y = eW[k * DIM + lane + 64];
        wr23[k].x = eW[k * DIM + lane + 128];
        wr23[k].y = eW[k * DIM + lane + 192];
        wr4[k] = dv4 ? eW[k * DIM + d4] : 0.f;
    }
    f32x2 eb01 = {eb[lane], eb[lane + 64]};
    f32x2 eb23 = {eb[lane + 128], eb[lane + 192]};
    float eb4 = dv4 ? eb[d4] : 0.f;

    const float* __restrict__ hv = hn + (size_t)v * HSTR;
    f32x2 acc01 = {hv[lane], hv[lane + 64]};
    f32x2 acc23 = {hv[lane + 128], hv[lane + 192]};
    float acc4 = hv[d4];   // pad reads 0

    const int j0 = (v == 0) ? 0 : P[v - 1];
    const int j1 = P[v];
    const f32x2 z2 = {0.f, 0.f};

    int j = j0;
    for (; j + 4 <= j1; j += 4) {
        int s0 = __builtin_amdgcn_readfirstlane(es[j]);
        int s1 = __builtin_amdgcn_readfirstlane(es[j + 1]);
        int s2 = __builtin_amdgcn_readfirstlane(es[j + 2]);
        int s3 = __builtin_amdgcn_readfirstlane(es[j + 3]);
        const float* __restrict__ h0 = hn + (size_t)s0 * HSTR;
        const float* __restrict__ h1 = hn + (size_t)s1 * HSTR;
        const float* __restrict__ h2p = hn + (size_t)s2 * HSTR;
        const float* __restrict__ h3 = hn + (size_t)s3 * HSTR;
        f32x2 hva[4], hvb[4];
        float hvc[4];
        const float* __restrict__ hp[4] = {h0, h1, h2p, h3};
#pragma unroll
        for (int u = 0; u < 4; ++u) {
            hva[u].x = hp[u][lane];       hva[u].y = hp[u][lane + 64];
            hvb[u].x = hp[u][lane + 128]; hvb[u].y = hp[u][lane + 192];
            hvc[u] = hp[u][d4];
        }
#pragma unroll
        for (int u = 0; u < 4; ++u) {
            f32x2 he01, he23; float he4;
            he_edge(efsb, j + u, wr01, wr23, wr4, eb01, eb23, eb4, he01, he23, he4);
            acc01 += __builtin_elementwise_max(hva[u] + he01, z2);
            acc23 += __builtin_elementwise_max(hvb[u] + he23, z2);
            acc4 += fmaxf(hvc[u] + he4, 0.f);
        }
    }
    for (; j < j1; ++j) {
        int s = __builtin_amdgcn_readfirstlane(es[j]);
        const float* __restrict__ hp = hn + (size_t)s * HSTR;
        f32x2 ha = {hp[lane], hp[lane + 64]};
        f32x2 hb = {hp[lane + 128], hp[lane + 192]};
        float hc = hp[d4];
        f32x2 he01, he23; float he4;
        he_edge(efsb, j, wr01, wr23, wr4, eb01, eb23, eb4, he01, he23, he4);
        acc01 += __builtin_elementwise_max(ha + he01, z2);
        acc23 += __builtin_elementwise_max(hb + he23, z2);
        acc4 += fmaxf(hc + he4, 0.f);
    }

    unsigned short* __restrict__ op = aggH + (size_t)v * HSTR;
    op[lane] = f2bf(acc01.x);
    op[lane + 64] = f2bf(acc01.y);
    op[lane + 128] = f2bf(acc23.x);
    op[lane + 192] = f2bf(acc23.y);
    op[d4] = dv4 ? f2bf(acc4) : (unsigned short)0;
}

// ---------------------------------------------------------------------------
// BN finalize + apply (hn stride 320, compact cols 0..299)
// ---------------------------------------------------------------------------
__global__ __launch_bounds__(256) void bn_finalize(
    const float* __restrict__ stats, const float* __restrict__ g,
    const float* __restrict__ beta, float* __restrict__ ab, int C)
{
    int c = blockIdx.x * 256 + threadIdx.x;
    if (c >= C) return;
    const float invN = 1.f / (float)N_NODES;
    float m = stats[c] * invN;
    float v = stats[C + c] * invN - m * m;
    float a = g[c] * rsqrtf(v + BN_EPS);
    ab[c] = a;
    ab[C + c] = beta[c] - m * a;
}

__global__ __launch_bounds__(256) void bn_apply_s(
    const float* __restrict__ x, const float* __restrict__ ab,
    float* __restrict__ y, int relu)
{
    int i = blockIdx.x * 256 + threadIdx.x;
    if (i >= N_NODES * 75) return;     // 75 float4 per 300-col row
    int n = i / 75;
    int c = (i - n * 75) * 4;
    size_t o = (size_t)n * (HSTR / 4) + (c >> 2);
    float4 v = ((const float4*)x)[o];
    const float* a = ab + c;
    const float* bb = ab + DIM + c;
    float4 r;
    r.x = fmaf(v.x, a[0], bb[0]);
    r.y = fmaf(v.y, a[1], bb[1]);
    r.z = fmaf(v.z, a[2], bb[2]);
    r.w = fmaf(v.w, a[3], bb[3]);
    if (relu) {
        r.x = fmaxf(r.x, 0.f); r.y = fmaxf(r.y, 0.f);
        r.z = fmaxf(r.z, 0.f); r.w = fmaxf(r.w, 0.f);
    }
    ((float4*)y)[o] = r;
}

// ---------------------------------------------------------------------------
// Mean pooling (hn stride 320) fused with last BN affine.
// ---------------------------------------------------------------------------
__global__ __launch_bounds__(256) void pool_seg_bn(
    const float* __restrict__ h2, const int* __restrict__ gid,
    const float* __restrict__ ab, float* __restrict__ hg)
{
    const int g = blockIdx.x;
    int lo = 0, hi = N_NODES;
    while (lo < hi) { int mid = (lo + hi) >> 1; if (gid[mid] < g) lo = mid + 1; else hi = mid; }
    int lo2 = lo, hi2 = N_NODES;
    while (lo2 < hi2) { int mid = (lo2 + hi2) >> 1; if (gid[mid] < g + 1) lo2 = mid + 1; else hi2 = mid; }
    const float inv = 1.f / fmaxf((float)(lo2 - lo), 1.f);
    for (int d = threadIdx.x; d < DIM; d += 256) {
        float s = 0.f;
        for (int r = lo; r < lo2; ++r) s += h2[(size_t)r * HSTR + d];
        hg[(size_t)g * DIM + d] = fmaf(s * inv, ab[d], ab[DIM + d]);
    }
}

// fp32 tiled sgemm for the tiny prediction head
#define TS 64
#define BK 16
#define ASP 68

__global__ __launch_bounds__(256) void sgemm_bias(
    const float* __restrict__ A, const float* __restrict__ B,
    const float* __restrict__ bias, float* __restrict__ C,
    int M, int Ncol, int K)
{
    __shared__ float As[BK][ASP];
    __shared__ float Bs[BK][TS];
    const int tid = threadIdx.x;
    const int bm = blockIdx.x * TS;
    const int bn = blockIdx.y * TS;
    const int tm = (tid >> 4) * 4;
    const int tn = (tid & 15) * 4;
    float acc[4][4] = {};

    for (int k0 = 0; k0 < K; k0 += BK) {
#pragma unroll
        for (int i = 0; i < 4; ++i) {
            int idx = tid + i * 256;
            int m = idx >> 4;
            int k = idx & 15;
            int row = bm + m, kk = k0 + k;
            float v = 0.f;
            if (row < M && kk < K) v = A[(size_t)row * K + kk];
            As[k][m] = v;
        }
#pragma unroll
        for (int i = 0; i < 4; ++i) {
            int idx = tid + i * 256;
            int k = idx >> 6;
            int n = idx & 63;
            int col = bn + n, kk = k0 + k;
            float v = 0.f;
            if (col < Ncol && kk < K) v = B[(size_t)kk * Ncol + col];
            Bs[k][n] = v;
        }
        __syncthreads();
#pragma unroll
        for (int k = 0; k < BK; ++k) {
            float4 av = *(const float4*)&As[k][tm];
            float4 bv = *(const float4*)&Bs[k][tn];
            float a4[4] = {av.x, av.y, av.z, av.w};
            float b4[4] = {bv.x, bv.y, bv.z, bv.w};
#pragma unroll
            for (int i = 0; i < 4; ++i)
#pragma unroll
                for (int j = 0; j < 4; ++j)
                    acc[i][j] = fmaf(a4[i], b4[j], acc[i][j]);
        }
        __syncthreads();
    }

#pragma unroll
    for (int i = 0; i < 4; ++i) {
        int row = bm + tm + i;
        if (row >= M) continue;
#pragma unroll
        for (int j = 0; j < 4; ++j) {
            int col = bn + tn + j;
            if (col < Ncol)
                C[(size_t)row * Ncol + col] = acc[i][j] + bias[col];
        }
    }
}

// ---------------------------------------------------------------------------
extern "C" void kernel_launch(void* const* d_in, const int* in_sizes, int n_in,
                              void* d_out, int out_size, void* d_ws, size_t ws_size,
                              hipStream_t stream)
{
    const float* node_feat = (const float*)d_in[0];
    const float* edge_feat = (const float*)d_in[1];
    const int*   src       = (const int*)d_in[2];
    const int*   dst       = (const int*)d_in[3];
    const int*   gid       = (const int*)d_in[4];
    const float* node_W = (const float*)d_in[6];
    const float* node_b = (const float*)d_in[7];
    const float* edge_W = (const float*)d_in[8];
    const float* edge_b = (const float*)d_in[9];
    const float* W1  = (const float*)d_in[10];
    const float* b1  = (const float*)d_in[11];
    const float* g1  = (const float*)d_in[12];
    const float* be1 = (const float*)d_in[13];
    const float* W2  = (const float*)d_in[14];
    const float* b2  = (const float*)d_in[15];
    const float* g2  = (const float*)d_in[16];
    const float* be2 = (const float*)d_in[17];
    const float* pred_W = (const float*)d_in[18];
    const float* pred_b = (const float*)d_in[19];
    float* out = (float*)d_out;

    // ---- workspace layout (bytes), total ~187.5 MB ----
    char* base = (char*)d_ws;
    float* hn            = (float*)(base + 0);                 // 64,000,000 (50000x320 fp32)
    float* h2            = hn;                                 // in-place
    unsigned short* x1b  = (unsigned short*)(base + 64000000); // 60,000,000 (50000x600 bf16)
    unsigned short* nfH  = (unsigned short*)x1b;               // 12.8M alias (encoder only)
    int*   eids          = (int*)(base + 80000000);            // 3.2M alias in x1b (preamble only)
    unsigned short* aggH = (unsigned short*)(base + 124000000);// 32,000,000 (50000x320 bf16)
    int*   es            = (int*)(base + 156000000);           // 3,200,000
    unsigned short* efsb = (unsigned short*)(base + 159200000);// 25,600,000
    unsigned short* wtH  = (unsigned short*)(base + 184800000);// <=500,000
    unsigned short* wtL  = (unsigned short*)(base + 185800000);
    int*   P             = (int*)(base + 186800000);           // 200,004
    float* stats         = (float*)(base + 187000016);
    float* ab            = (float*)(base + 187007216);
    float* hg            = (float*)(base + 187014416);         // 307,200
    float* stats2        = stats + 1200;
    float* ab2           = ab + 1200;

    dim3 blk(256);

    // zero hn (pads must be 0; ws is poisoned 0xAA each launch)
    hipMemsetAsync(hn, 0, (size_t)N_NODES * HSTR * sizeof(float), stream);

    // ---- node encoder: hn = node_feat @ node_W + node_b (stride 320) ----
    tobf4<<<dim3((N_NODES * NFEAT / 4 + 255) / 256), blk, 0, stream>>>(
        node_feat, nfH, N_NODES * NFEAT / 4);
    conv_wt<<<dim3((384 * 128 + 255) / 256), blk, 0, stream>>>(
        node_W, wtH, wtL, NFEAT, DIM, 128, 384);
    gemm_pp<<<dim3(391, 3), blk, 0, stream>>>(
        nfH, wtH, wtL, node_b, hn, HSTR, nullptr, 0, N_NODES, DIM, 128, nullptr);

    // ---- CSR by dst + packed edge streams (layer-invariant, run once) ----
    hipMemsetAsync(P, 0, (N_NODES + 1) * sizeof(int), stream);
    csr_count<<<dim3((N_EDGES + 255) / 256), blk, 0, stream>>>(dst, P);
    csr_scan<<<dim3(1), dim3(1024), 0, stream>>>(P);
    csr_fill<<<dim3((N_EDGES + 255) / 256), blk, 0, stream>>>(dst, P, eids);
    edge_pack_bf<<<dim3((N_EDGES + 255) / 256), blk, 0, stream>>>(
        src, eids, edge_feat, es, efsb);

    for (int l = 0; l < N_LAYERS; ++l) {
        // aggH = bf16(hn + sum relu(hn[src] + he))  [N][320]
        gather_agg8<<<dim3((N_NODES + 3) / 4), blk, 0, stream>>>(
            hn, efsb, es, P,
            edge_W + (size_t)l * EFEAT * DIM, edge_b + (size_t)l * DIM, aggH);

        hipMemsetAsync(stats, 0, 1800 * sizeof(float), stream);

        // x1b = bf16(agg @ W1 + b1)  [N,600] (+ BN1 stats from exact fp32 acc)
        conv_wt<<<dim3((640 * 320 + 255) / 256), blk, 0, stream>>>(
            W1 + (size_t)l * DIM * 2 * DIM, wtH, wtL, DIM, 2 * DIM, 320, 640);
        gemm_pp<<<dim3(391, 5), blk, 0, stream>>>(
            aggH, wtH, wtL, b1 + (size_t)l * 2 * DIM, nullptr, 0, x1b, 600,
            N_NODES, 2 * DIM, 320, stats);
        bn_finalize<<<dim3(3), blk, 0, stream>>>(
            stats, g1 + (size_t)l * 2 * DIM, be1 + (size_t)l * 2 * DIM, ab, 2 * DIM);

        // h2(=hn) = relu(bn1(x1b)) @ W2 + b2  (BN1 fused in staging; BN2 stats)
        conv_wt<<<dim3((384 * 608 + 255) / 256), blk, 0, stream>>>(
            W2 + (size_t)l * 2 * DIM * DIM, wtH, wtL, 2 * DIM, DIM, 608, 384);
        gemm_af<<<dim3(391, 3), blk, 0, stream>>>(
            x1b, 600, wtH, wtL, b2 + (size_t)l * DIM, h2, HSTR,
            N_NODES, DIM, 2 * DIM, 608, ab, stats2);
        bn_finalize<<<dim3(2), blk, 0, stream>>>(
            stats2, g2 + (size_t)l * DIM, be2 + (size_t)l * DIM, ab2, DIM);

        // hn = bn2(h2) + relu, in place — except last layer (fused into pool)
        if (l < N_LAYERS - 1)
            bn_apply_s<<<dim3((N_NODES * 75 + 255) / 256), blk, 0, stream>>>(
                h2, ab2, hn, 1);
    }

    // ---- mean pool with fused last-BN affine + head ----
    pool_seg_bn<<<dim3(N_GRAPHS), blk, 0, stream>>>(h2, gid, ab2, hg);
    sgemm_bias<<<dim3((N_GRAPHS + 63) / 64, (OUTD + 63) / 64), blk, 0, stream>>>(
        hg, pred_W, pred_b, out, N_GRAPHS, OUTD, DIM);
}

// Round 11
// 1973.437 us; speedup vs baseline: 1.2336x; 1.2336x over previous
//
#include <hip/hip_runtime.h>

#define N_NODES 50000
#define N_EDGES 800000
#define N_GRAPHS 256
#define N_LAYERS 3
#define DIM 300
#define NFEAT 128
#define EFEAT 16
#define OUTD 128
#define BN_EPS 1e-5f

typedef __attribute__((ext_vector_type(8))) short bfrag8;   // 8 bf16 = 4 VGPR (MFMA A/B operand)
typedef __attribute__((ext_vector_type(4))) float facc4;    // MFMA C/D
typedef __attribute__((ext_vector_type(4))) unsigned short us4;
typedef __attribute__((ext_vector_type(8))) unsigned short us8;

// ---------------- bf16 helpers (RNE) + hi/lo split ----------------
__device__ __forceinline__ unsigned short f2bf(float f) {
    unsigned u = __float_as_uint(f);
    unsigned r = ((u >> 16) & 1u) + 0x7fffu;
    return (unsigned short)((u + r) >> 16);
}
__device__ __forceinline__ float bf2f(unsigned short h) {
    return __uint_as_float(((unsigned)h) << 16);
}
__device__ __forceinline__ void split2(float v, unsigned short& h, unsigned short& l) {
    h = f2bf(v);
    l = f2bf(v - bf2f(h));
}

// async global->LDS, 16B per lane. LDS dest = uniform base + lane*16 (HW rule).
__device__ __forceinline__ void load_lds16(const void* gsrc, void* ldsdst) {
    __builtin_amdgcn_global_load_lds(
        (const __attribute__((address_space(1))) unsigned int*)gsrc,
        (__attribute__((address_space(3))) unsigned int*)ldsdst,
        16, 0, 0);
}

#define MFMA16(a, b, c) __builtin_amdgcn_mfma_f32_16x16x32_bf16(a, b, c, 0, 0, 0)

// ---------------------------------------------------------------------------
// fp32 -> bf16 (hi only), vectorized
// ---------------------------------------------------------------------------
__global__ __launch_bounds__(256) void tobf4(
    const float* __restrict__ x, unsigned short* __restrict__ H, int n4)
{
    int i = blockIdx.x * 256 + threadIdx.x;
    if (i >= n4) return;
    float4 v = ((const float4*)x)[i];
    us4 h;
    h.x = f2bf(v.x); h.y = f2bf(v.y); h.z = f2bf(v.z); h.w = f2bf(v.w);
    ((us4*)H)[i] = h;
}

// ---------------------------------------------------------------------------
// weight conversion: W fp32 [K][N] -> transposed padded hi/lo planes [Np][Kp]
// ---------------------------------------------------------------------------
__global__ __launch_bounds__(256) void conv_wt(
    const float* __restrict__ W, unsigned short* __restrict__ H,
    unsigned short* __restrict__ L, int K, int N, int Kp, int Np)
{
    int idx = blockIdx.x * 256 + threadIdx.x;
    if (idx >= Np * Kp) return;
    int n = idx / Kp;
    int k = idx - n * Kp;
    float v = (n < N && k < K) ? W[(size_t)k * N + n] : 0.f;
    unsigned short h, l;
    split2(v, h, l);
    H[idx] = h;
    L[idx] = l;
}

// ---------------------------------------------------------------------------
// bf16 MFMA GEMM: A plain bf16 [M][Kp]; B transposed hi/lo planes [Np][Kp].
// acc = Ah*Bh + Ah*Bl (2 MFMA/tile). Block 128x128, BK=32, 4 waves 2x2.
// GRID: blockIdx.x = N-block (fast-varying) so consecutive blocks share the
// same A row-tile -> A L2 reuse across column blocks. blockIdx.y = M-block.
// LDS 24KB: A | Bh | Bl. Optional column-stat epilogue (BN).
// ---------------------------------------------------------------------------
__global__ __launch_bounds__(256, 2) void gemm_pp(
    const unsigned short* __restrict__ Ah,
    const unsigned short* __restrict__ Bth, const unsigned short* __restrict__ Btl,
    const float* __restrict__ bias, float* __restrict__ C,
    int M, int N, int Kp, float* __restrict__ stats)
{
    __shared__ unsigned short lds[12288];   // 24 KB
    const int tid = threadIdx.x;
    const int lane = tid & 63;
    const int w = tid >> 6;
    const int m0 = blockIdx.y * 128;
    const int n0 = blockIdx.x * 128;
    const int wm = (w & 1) * 64;
    const int wn = (w >> 1) * 64;

    const int srow = lane >> 2;
    const int scol = (lane & 3) * 8;

    const unsigned short* gp[6];
    unsigned loff[6];
#pragma unroll
    for (int i = 0; i < 6; ++i) {
        int c = w * 6 + i;
        const unsigned short* pl = (c < 8) ? Ah : (c < 16) ? Bth : Btl;
        int rowg;
        if (c < 8) {
            rowg = m0 + (c & 7) * 16 + srow;
            rowg = min(rowg, M - 1);
        } else {
            rowg = n0 + (c & 7) * 16 + srow;
        }
        gp[i] = pl + (size_t)rowg * Kp + scol;
        loff[i] = c * 512;
    }

    facc4 acc[4][4];
    facc4 zero = {0.f, 0.f, 0.f, 0.f};
#pragma unroll
    for (int i = 0; i < 4; ++i)
#pragma unroll
        for (int j = 0; j < 4; ++j) acc[i][j] = zero;

    const int fr = lane & 15;
    const int fq = (lane >> 4) * 8;

    for (int k0 = 0; k0 < Kp; k0 += 32) {
#pragma unroll
        for (int i = 0; i < 6; ++i) {
            load_lds16(gp[i], &lds[loff[i]]);
            gp[i] += 32;
        }
        __syncthreads();

        bfrag8 ah[4], bh[4], bl[4];
#pragma unroll
        for (int t = 0; t < 4; ++t) {
            int ar = wm + t * 16 + fr;
            ah[t] = *(const bfrag8*)&lds[ar * 32 + fq];
            int br = wn + t * 16 + fr;
            bh[t] = *(const bfrag8*)&lds[4096 + br * 32 + fq];
            bl[t] = *(const bfrag8*)&lds[8192 + br * 32 + fq];
        }
#pragma unroll
        for (int i = 0; i < 4; ++i)
#pragma unroll
            for (int j = 0; j < 4; ++j) {
                acc[i][j] = MFMA16(ah[i], bh[j], acc[i][j]);
                acc[i][j] = MFMA16(ah[i], bl[j], acc[i][j]);
            }
        __syncthreads();
    }

    // epilogue: C/D layout col=lane&15, row=(lane>>4)*4+reg
#pragma unroll
    for (int i = 0; i < 4; ++i)
#pragma unroll
        for (int j = 0; j < 4; ++j) {
            int col = n0 + wn + j * 16 + (lane & 15);
            if (col >= N) continue;
            float bv = bias[col];
#pragma unroll
            for (int r = 0; r < 4; ++r) {
                int row = m0 + wm + i * 16 + (lane >> 4) * 4 + r;
                if (row < M)
                    C[(size_t)row * N + col] = acc[i][j][r] + bv;
            }
        }

    if (stats != nullptr) {
#pragma unroll
        for (int j = 0; j < 4; ++j) {
            int col = n0 + wn + j * 16 + (lane & 15);
            float cs = 0.f, cq = 0.f;
            if (col < N) {
                float bv = bias[col];
#pragma unroll
                for (int i = 0; i < 4; ++i)
#pragma unroll
                    for (int r = 0; r < 4; ++r) {
                        int row = m0 + wm + i * 16 + (lane >> 4) * 4 + r;
                        if (row < M) {
                            float y = acc[i][j][r] + bv;
                            cs += y;
                            cq = fmaf(y, y, cq);
                        }
                    }
            }
            cs += __shfl_xor(cs, 16, 64); cq += __shfl_xor(cq, 16, 64);
            cs += __shfl_xor(cs, 32, 64); cq += __shfl_xor(cq, 32, 64);
            if ((lane >> 4) == 0 && col < N) {
                atomicAdd(&stats[col], cs);
                atomicAdd(&stats[N + col], cq);
            }
        }
    }
}

// ---------------------------------------------------------------------------
// bf16 MFMA GEMM, A fp32 with fused BN-affine+ReLU applied during staging
// (abn = [a K | b K], y = relu(x*a+b)) -> bf16 hi only. Grid transposed as
// gemm_pp (x=N-block) for A L2 reuse. Column-stat epilogue for BN2.
// ---------------------------------------------------------------------------
__global__ __launch_bounds__(256, 2) void gemm_af(
    const float* __restrict__ A, const unsigned short* __restrict__ Bth,
    const unsigned short* __restrict__ Btl, const float* __restrict__ bias,
    float* __restrict__ C, int M, int N, int K, int Kp,
    const float* __restrict__ abn, float* __restrict__ stats)
{
    __shared__ unsigned short lds[12288];
    const int tid = threadIdx.x;
    const int lane = tid & 63;
    const int w = tid >> 6;
    const int m0 = blockIdx.y * 128;
    const int n0 = blockIdx.x * 128;
    const int wm = (w & 1) * 64;
    const int wn = (w >> 1) * 64;

    const int srow = lane >> 2;
    const int scol = (lane & 3) * 8;

    const unsigned short* gpb[4];
    unsigned loffb[4];
#pragma unroll
    for (int i = 0; i < 4; ++i) {
        int c = w * 4 + i;
        const unsigned short* pl = (c < 8) ? Bth : Btl;
        int rowg = n0 + (c & 7) * 16 + srow;
        gpb[i] = pl + (size_t)rowg * Kp + scol;
        loffb[i] = 4096 + c * 512;
    }

    facc4 acc[4][4];
    facc4 zero = {0.f, 0.f, 0.f, 0.f};
#pragma unroll
    for (int i = 0; i < 4; ++i)
#pragma unroll
        for (int j = 0; j < 4; ++j) acc[i][j] = zero;

    const int fr = lane & 15;
    const int fq = (lane >> 4) * 8;

    for (int k0 = 0; k0 < Kp; k0 += 32) {
#pragma unroll
        for (int i = 0; i < 4; ++i) {
            load_lds16(gpb[i], &lds[loffb[i]]);
            gpb[i] += 32;
        }
        // A fp32 -> BN affine + relu -> bf16 into LDS (128 rows x 32 k)
#pragma unroll
        for (int i = 0; i < 4; ++i) {
            int idx = tid + i * 256;
            int row = idx >> 3;
            int q4 = idx & 7;
            int rg = min(m0 + row, M - 1);
            int kk = k0 + q4 * 4;
            us4 h;
            if (kk < K) {
                float4 v = *(const float4*)&A[(size_t)rg * K + kk];
                float4 sa = *(const float4*)&abn[kk];
                float4 sb = *(const float4*)&abn[K + kk];
                h.x = f2bf(fmaxf(fmaf(v.x, sa.x, sb.x), 0.f));
                h.y = f2bf(fmaxf(fmaf(v.y, sa.y, sb.y), 0.f));
                h.z = f2bf(fmaxf(fmaf(v.z, sa.z, sb.z), 0.f));
                h.w = f2bf(fmaxf(fmaf(v.w, sa.w, sb.w), 0.f));
            } else {
                h.x = 0; h.y = 0; h.z = 0; h.w = 0;
            }
            *(us4*)&lds[row * 32 + q4 * 4] = h;
        }
        __syncthreads();

        bfrag8 ah[4], bh[4], bl[4];
#pragma unroll
        for (int t = 0; t < 4; ++t) {
            int ar = wm + t * 16 + fr;
            ah[t] = *(const bfrag8*)&lds[ar * 32 + fq];
            int br = wn + t * 16 + fr;
            bh[t] = *(const bfrag8*)&lds[4096 + br * 32 + fq];
            bl[t] = *(const bfrag8*)&lds[8192 + br * 32 + fq];
        }
#pragma unroll
        for (int i = 0; i < 4; ++i)
#pragma unroll
            for (int j = 0; j < 4; ++j) {
                acc[i][j] = MFMA16(ah[i], bh[j], acc[i][j]);
                acc[i][j] = MFMA16(ah[i], bl[j], acc[i][j]);
            }
        __syncthreads();
    }

#pragma unroll
    for (int i = 0; i < 4; ++i)
#pragma unroll
        for (int j = 0; j < 4; ++j) {
            int col = n0 + wn + j * 16 + (lane & 15);
            if (col >= N) continue;
            float bv = bias[col];
#pragma unroll
            for (int r = 0; r < 4; ++r) {
                int row = m0 + wm + i * 16 + (lane >> 4) * 4 + r;
                if (row < M)
                    C[(size_t)row * N + col] = acc[i][j][r] + bv;
            }
        }

    if (stats != nullptr) {
#pragma unroll
        for (int j = 0; j < 4; ++j) {
            int col = n0 + wn + j * 16 + (lane & 15);
            float cs = 0.f, cq = 0.f;
            if (col < N) {
                float bv = bias[col];
#pragma unroll
                for (int i = 0; i < 4; ++i)
#pragma unroll
                    for (int r = 0; r < 4; ++r) {
                        int row = m0 + wm + i * 16 + (lane >> 4) * 4 + r;
                        if (row < M) {
                            float y = acc[i][j][r] + bv;
                            cs += y;
                            cq = fmaf(y, y, cq);
                        }
                    }
            }
            cs += __shfl_xor(cs, 16, 64); cq += __shfl_xor(cq, 16, 64);
            cs += __shfl_xor(cs, 32, 64); cq += __shfl_xor(cq, 32, 64);
            if ((lane >> 4) == 0 && col < N) {
                atomicAdd(&stats[col], cs);
                atomicAdd(&stats[N + col], cq);
            }
        }
    }
}

// ---------------------------------------------------------------------------
// CSR build (dst-sorted). P[v] = end offset after fill.
// ---------------------------------------------------------------------------
__global__ __launch_bounds__(256) void csr_count(const int* __restrict__ dst, int* __restrict__ P)
{
    int e = blockIdx.x * 256 + threadIdx.x;
    if (e < N_EDGES) atomicAdd(&P[dst[e] + 1], 1);
}

__global__ __launch_bounds__(1024) void csr_scan(int* __restrict__ P)
{
    __shared__ int part[1024];
    const int t = threadIdx.x;
    const int CH = 49;
    int i0 = t * CH;
    int s = 0;
    for (int i = i0; i < i0 + CH; ++i) {
        if (i <= N_NODES) { s += P[i]; P[i] = s; }
    }
    part[t] = s;
    __syncthreads();
    if (t == 0) {
        int run = 0;
        for (int k = 0; k < 1024; ++k) { int tmp = part[k]; part[k] = run; run += tmp; }
    }
    __syncthreads();
    int off = part[t];
    for (int i = i0; i < i0 + CH; ++i) {
        if (i <= N_NODES) P[i] += off;
    }
}

__global__ __launch_bounds__(256) void csr_fill(
    const int* __restrict__ dst, int* __restrict__ P, int* __restrict__ eids)
{
    int e = blockIdx.x * 256 + threadIdx.x;
    if (e < N_EDGES) {
        int pos = atomicAdd(&P[dst[e]], 1);
        eids[pos] = e;
    }
}

// ---------------------------------------------------------------------------
// Re-sort src + edge_feat(->bf16) into CSR edge order. Runs once.
// ---------------------------------------------------------------------------
__global__ __launch_bounds__(256) void edge_pack_bf(
    const int* __restrict__ src, const int* __restrict__ eids,
    const float* __restrict__ edge_feat, int* __restrict__ es,
    unsigned short* __restrict__ efsb)
{
    int j = blockIdx.x * 256 + threadIdx.x;
    if (j >= N_EDGES) return;
    int e = eids[j];
    es[j] = src[e];
    const float* sp = edge_feat + (size_t)e * EFEAT;
    us8 o0, o1;
#pragma unroll
    for (int k = 0; k < 8; ++k) {
        o0[k] = f2bf(sp[k]);
        o1[k] = f2bf(sp[8 + k]);
    }
    *(us8*)&efsb[(size_t)j * EFEAT] = o0;
    *(us8*)&efsb[(size_t)j * EFEAT + 8] = o1;
}

// ---------------------------------------------------------------------------
// Gather aggregation v7 (r9-proven, 224us/layer): ONE wave per node, fp32 hn
// rows compact stride 300 (1200B — non-power-of-2 keeps HBM channels spread;
// r10's 1280B stride caused channel camping), x4 edge unroll = 20 outstanding
// row loads, ef loads hoisted ahead of the math. Output bf16 [N][320].
// ---------------------------------------------------------------------------
__global__ __launch_bounds__(256) void gather_agg7(
    const float* __restrict__ hn, const unsigned short* __restrict__ efsb,
    const int* __restrict__ es, const int* __restrict__ P,
    const float* __restrict__ eW, const float* __restrict__ eb,
    unsigned short* __restrict__ aggH)
{
    const int v = blockIdx.x * 4 + (threadIdx.x >> 6);
    if (v >= N_NODES) return;
    const int lane = threadIdx.x & 63;

    float wr[EFEAT][5];
    float acc[5];
    float ebv[5];
#pragma unroll
    for (int c = 0; c < 5; ++c) {
        int d = lane + 64 * c;
        bool dv = d < DIM;
        acc[c] = dv ? hn[(size_t)v * DIM + d] : 0.f;
        ebv[c] = dv ? eb[d] : 0.f;
#pragma unroll
        for (int k = 0; k < EFEAT; ++k)
            wr[k][c] = dv ? eW[k * DIM + d] : 0.f;
    }

    const int j0 = (v == 0) ? 0 : P[v - 1];
    const int j1 = P[v];

    int j = j0;
    for (; j + 4 <= j1; j += 4) {
        int s0 = __builtin_amdgcn_readfirstlane(es[j]);
        int s1 = __builtin_amdgcn_readfirstlane(es[j + 1]);
        int s2 = __builtin_amdgcn_readfirstlane(es[j + 2]);
        int s3 = __builtin_amdgcn_readfirstlane(es[j + 3]);
        const float* __restrict__ h0 = hn + (size_t)s0 * DIM;
        const float* __restrict__ h1 = hn + (size_t)s1 * DIM;
        const float* __restrict__ h2p = hn + (size_t)s2 * DIM;
        const float* __restrict__ h3 = hn + (size_t)s3 * DIM;
        float hv[4][5];
#pragma unroll
        for (int c = 0; c < 5; ++c) {
            int d = lane + 64 * c;
            bool dv = d < DIM;
            hv[0][c] = dv ? h0[d] : 0.f;
            hv[1][c] = dv ? h1[d] : 0.f;
            hv[2][c] = dv ? h2p[d] : 0.f;
            hv[3][c] = dv ? h3[d] : 0.f;
        }
        us8 pk[4][2];
#pragma unroll
        for (int u = 0; u < 4; ++u) {
            pk[u][0] = *(const us8*)&efsb[(size_t)(j + u) * EFEAT];
            pk[u][1] = *(const us8*)&efsb[(size_t)(j + u) * EFEAT + 8];
        }
#pragma unroll
        for (int u = 0; u < 4; ++u) {
            float ef[EFEAT];
#pragma unroll
            for (int k = 0; k < 8; ++k) {
                ef[k] = bf2f(pk[u][0][k]);
                ef[8 + k] = bf2f(pk[u][1][k]);
            }
#pragma unroll
            for (int c = 0; c < 5; ++c) {
                float he = ebv[c];
#pragma unroll
                for (int k = 0; k < EFEAT; ++k) he = fmaf(ef[k], wr[k][c], he);
                acc[c] += fmaxf(hv[u][c] + he, 0.f);
            }
        }
    }
    for (; j < j1; ++j) {
        int s = __builtin_amdgcn_readfirstlane(es[j]);
        const float* __restrict__ hp = hn + (size_t)s * DIM;
        float hv[5];
#pragma unroll
        for (int c = 0; c < 5; ++c) {
            int d = lane + 64 * c;
            hv[c] = (d < DIM) ? hp[d] : 0.f;
        }
        us8 p0 = *(const us8*)&efsb[(size_t)j * EFEAT];
        us8 p1 = *(const us8*)&efsb[(size_t)j * EFEAT + 8];
        float ef[EFEAT];
#pragma unroll
        for (int k = 0; k < 8; ++k) {
            ef[k] = bf2f(p0[k]);
            ef[8 + k] = bf2f(p1[k]);
        }
#pragma unroll
        for (int c = 0; c < 5; ++c) {
            float he = ebv[c];
#pragma unroll
            for (int k = 0; k < EFEAT; ++k) he = fmaf(ef[k], wr[k][c], he);
            acc[c] += fmaxf(hv[c] + he, 0.f);
        }
    }

#pragma unroll
    for (int c = 0; c < 5; ++c)
        aggH[(size_t)v * 320 + lane + 64 * c] = f2bf(acc[c]);
}

// ---------------------------------------------------------------------------
// BN finalize + apply
// ---------------------------------------------------------------------------
__global__ __launch_bounds__(256) void bn_finalize(
    const float* __restrict__ stats, const float* __restrict__ g,
    const float* __restrict__ beta, float* __restrict__ ab, int C)
{
    int c = blockIdx.x * 256 + threadIdx.x;
    if (c >= C) return;
    const float invN = 1.f / (float)N_NODES;
    float m = stats[c] * invN;
    float v = stats[C + c] * invN - m * m;
    float a = g[c] * rsqrtf(v + BN_EPS);
    ab[c] = a;
    ab[C + c] = beta[c] - m * a;
}

__global__ __launch_bounds__(256) void bn_apply(
    const float* __restrict__ x, const float* __restrict__ ab,
    float* __restrict__ y, int total4, int C, int relu)
{
    int i = blockIdx.x * 256 + threadIdx.x;
    if (i >= total4) return;
    float4 v = ((const float4*)x)[i];
    int c = (i << 2) % C;
    const float* a = ab + c;
    const float* bb = ab + C + c;
    float4 r;
    r.x = fmaf(v.x, a[0], bb[0]);
    r.y = fmaf(v.y, a[1], bb[1]);
    r.z = fmaf(v.z, a[2], bb[2]);
    r.w = fmaf(v.w, a[3], bb[3]);
    if (relu) {
        r.x = fmaxf(r.x, 0.f); r.y = fmaxf(r.y, 0.f);
        r.z = fmaxf(r.z, 0.f); r.w = fmaxf(r.w, 0.f);
    }
    ((float4*)y)[i] = r;
}

// ---------------------------------------------------------------------------
// Mean pooling fused with last BN affine: hg = a*mean(h2)+b.
// ---------------------------------------------------------------------------
__global__ __launch_bounds__(256) void pool_seg_bn(
    const float* __restrict__ h2, const int* __restrict__ gid,
    const float* __restrict__ ab, float* __restrict__ hg)
{
    const int g = blockIdx.x;
    int lo = 0, hi = N_NODES;
    while (lo < hi) { int mid = (lo + hi) >> 1; if (gid[mid] < g) lo = mid + 1; else hi = mid; }
    int lo2 = lo, hi2 = N_NODES;
    while (lo2 < hi2) { int mid = (lo2 + hi2) >> 1; if (gid[mid] < g + 1) lo2 = mid + 1; else hi2 = mid; }
    const float inv = 1.f / fmaxf((float)(lo2 - lo), 1.f);
    for (int d = threadIdx.x; d < DIM; d += 256) {
        float s = 0.f;
        for (int r = lo; r < lo2; ++r) s += h2[(size_t)r * DIM + d];
        hg[(size_t)g * DIM + d] = fmaf(s * inv, ab[d], ab[DIM + d]);
    }
}

// fp32 tiled sgemm for the tiny prediction head
#define TS 64
#define BK 16
#define ASP 68

__global__ __launch_bounds__(256) void sgemm_bias(
    const float* __restrict__ A, const float* __restrict__ B,
    const float* __restrict__ bias, float* __restrict__ C,
    int M, int Ncol, int K)
{
    __shared__ float As[BK][ASP];
    __shared__ float Bs[BK][TS];
    const int tid = threadIdx.x;
    const int bm = blockIdx.x * TS;
    const int bn = blockIdx.y * TS;
    const int tm = (tid >> 4) * 4;
    const int tn = (tid & 15) * 4;
    float acc[4][4] = {};

    for (int k0 = 0; k0 < K; k0 += BK) {
#pragma unroll
        for (int i = 0; i < 4; ++i) {
            int idx = tid + i * 256;
            int m = idx >> 4;
            int k = idx & 15;
            int row = bm + m, kk = k0 + k;
            float v = 0.f;
            if (row < M && kk < K) v = A[(size_t)row * K + kk];
            As[k][m] = v;
        }
#pragma unroll
        for (int i = 0; i < 4; ++i) {
            int idx = tid + i * 256;
            int k = idx >> 6;
            int n = idx & 63;
            int col = bn + n, kk = k0 + k;
            float v = 0.f;
            if (col < Ncol && kk < K) v = B[(size_t)kk * Ncol + col];
            Bs[k][n] = v;
        }
        __syncthreads();
#pragma unroll
        for (int k = 0; k < BK; ++k) {
            float4 av = *(const float4*)&As[k][tm];
            float4 bv = *(const float4*)&Bs[k][tn];
            float a4[4] = {av.x, av.y, av.z, av.w};
            float b4[4] = {bv.x, bv.y, bv.z, bv.w};
#pragma unroll
            for (int i = 0; i < 4; ++i)
#pragma unroll
                for (int j = 0; j < 4; ++j)
                    acc[i][j] = fmaf(a4[i], b4[j], acc[i][j]);
        }
        __syncthreads();
    }

#pragma unroll
    for (int i = 0; i < 4; ++i) {
        int row = bm + tm + i;
        if (row >= M) continue;
#pragma unroll
        for (int j = 0; j < 4; ++j) {
            int col = bn + tn + j;
            if (col < Ncol)
                C[(size_t)row * Ncol + col] = acc[i][j] + bias[col];
        }
    }
}

// ---------------------------------------------------------------------------
extern "C" void kernel_launch(void* const* d_in, const int* in_sizes, int n_in,
                              void* d_out, int out_size, void* d_ws, size_t ws_size,
                              hipStream_t stream)
{
    const float* node_feat = (const float*)d_in[0];
    const float* edge_feat = (const float*)d_in[1];
    const int*   src       = (const int*)d_in[2];
    const int*   dst       = (const int*)d_in[3];
    const int*   gid       = (const int*)d_in[4];
    const float* node_W = (const float*)d_in[6];
    const float* node_b = (const float*)d_in[7];
    const float* edge_W = (const float*)d_in[8];
    const float* edge_b = (const float*)d_in[9];
    const float* W1  = (const float*)d_in[10];
    const float* b1  = (const float*)d_in[11];
    const float* g1  = (const float*)d_in[12];
    const float* be1 = (const float*)d_in[13];
    const float* W2  = (const float*)d_in[14];
    const float* b2  = (const float*)d_in[15];
    const float* g2  = (const float*)d_in[16];
    const float* be2 = (const float*)d_in[17];
    const float* pred_W = (const float*)d_in[18];
    const float* pred_b = (const float*)d_in[19];
    float* out = (float*)d_out;

    // ---- workspace layout (bytes), total < 248.73 MB (r9-proven) ----
    char* base = (char*)d_ws;
    float* hn            = (float*)(base + 0);                 // 60,000,000
    float* h2            = hn;                                 // in-place (hn dead after gather)
    float* x1            = (float*)(base + 60000000);          // 120,000,000
    unsigned short* nfH  = (unsigned short*)x1;                // alias (encoder only)
    unsigned short* aggH = (unsigned short*)(base + 180000000);// 32,000,000
    int*   es            = (int*)(base + 212000000);           // 3,200,000
    unsigned short* efsb = (unsigned short*)(base + 215200000);// 25,600,000
    unsigned short* wtH  = (unsigned short*)(base + 244000000);
    unsigned short* wtL  = (unsigned short*)(base + 244500000);
    int*   eids          = (int*)(base + 245000000);           // 3,200,000
    int*   P             = (int*)(base + 248200000);           // 200,004
    float* stats         = (float*)(base + 248400016);
    float* ab            = (float*)(base + 248407216);
    float* hg            = (float*)(base + 248414416);         // 307,200
    float* stats2        = stats + 1200;
    float* ab2           = ab + 1200;

    dim3 blk(256);

    // ---- node encoder: hn = node_feat @ node_W + node_b ----
    tobf4<<<dim3((N_NODES * NFEAT / 4 + 255) / 256), blk, 0, stream>>>(
        node_feat, nfH, N_NODES * NFEAT / 4);
    conv_wt<<<dim3((384 * 128 + 255) / 256), blk, 0, stream>>>(
        node_W, wtH, wtL, NFEAT, DIM, 128, 384);
    gemm_pp<<<dim3(3, 391), blk, 0, stream>>>(
        nfH, wtH, wtL, node_b, hn, N_NODES, DIM, 128, nullptr);

    // ---- CSR by dst + packed edge streams (layer-invariant, run once) ----
    hipMemsetAsync(P, 0, (N_NODES + 1) * sizeof(int), stream);
    csr_count<<<dim3((N_EDGES + 255) / 256), blk, 0, stream>>>(dst, P);
    csr_scan<<<dim3(1), dim3(1024), 0, stream>>>(P);
    csr_fill<<<dim3((N_EDGES + 255) / 256), blk, 0, stream>>>(dst, P, eids);
    edge_pack_bf<<<dim3((N_EDGES + 255) / 256), blk, 0, stream>>>(
        src, eids, edge_feat, es, efsb);

    for (int l = 0; l < N_LAYERS; ++l) {
        // aggH = bf16(hn + sum relu(hn[src] + he))  [N][320]
        gather_agg7<<<dim3((N_NODES + 3) / 4), blk, 0, stream>>>(
            hn, efsb, es, P,
            edge_W + (size_t)l * EFEAT * DIM, edge_b + (size_t)l * DIM, aggH);

        hipMemsetAsync(stats, 0, 1800 * sizeof(float), stream);

        // x1 = agg @ W1 + b1   [N, 600]  (+ BN1 stats in epilogue)
        conv_wt<<<dim3((640 * 320 + 255) / 256), blk, 0, stream>>>(
            W1 + (size_t)l * DIM * 2 * DIM, wtH, wtL, DIM, 2 * DIM, 320, 640);
        gemm_pp<<<dim3(5, 391), blk, 0, stream>>>(
            aggH, wtH, wtL, b1 + (size_t)l * 2 * DIM, x1,
            N_NODES, 2 * DIM, 320, stats);
        bn_finalize<<<dim3(3), blk, 0, stream>>>(
            stats, g1 + (size_t)l * 2 * DIM, be1 + (size_t)l * 2 * DIM, ab, 2 * DIM);

        // h2(=hn) = relu(bn1(x1)) @ W2 + b2  (BN1 fused in staging; BN2 stats)
        conv_wt<<<dim3((384 * 608 + 255) / 256), blk, 0, stream>>>(
            W2 + (size_t)l * 2 * DIM * DIM, wtH, wtL, 2 * DIM, DIM, 608, 384);
        gemm_af<<<dim3(3, 391), blk, 0, stream>>>(
            x1, wtH, wtL, b2 + (size_t)l * DIM, h2, N_NODES, DIM, 2 * DIM, 608,
            ab, stats2);
        bn_finalize<<<dim3(2), blk, 0, stream>>>(
            stats2, g2 + (size_t)l * DIM, be2 + (size_t)l * DIM, ab2, DIM);

        // hn = bn2(h2) + relu, in place — except last layer (fused into pool)
        if (l < N_LAYERS - 1)
            bn_apply<<<dim3((N_NODES * DIM / 4 + 255) / 256), blk, 0, stream>>>(
                h2, ab2, hn, N_NODES * DIM / 4, DIM, 1);
    }

    // ---- mean pool with fused last-BN affine + head ----
    pool_seg_bn<<<dim3(N_GRAPHS), blk, 0, stream>>>(h2, gid, ab2, hg);
    sgemm_bias<<<dim3((N_GRAPHS + 63) / 64, (OUTD + 63) / 64), blk, 0, stream>>>(
        hg, pred_W, pred_b, out, N_GRAPHS, OUTD, DIM);
}